// Round 2
// baseline (494.959 us; speedup 1.0000x reference)
//
#include <hip/hip_runtime.h>
#include <hip/hip_bf16.h>
#include <math.h>

#define M_TOT   16384      // B*N = 4*4096
#define F_DIM   768
#define C_DIM   64
#define P_DIM   8192
#define EPSN    1e-12f
#define NEG_BIG (-3.402823466e38f)
#define NCH     8
#define PCH     (P_DIM / NCH)   // 1024
#define TAU     1e-3f

typedef __attribute__((ext_vector_type(8))) short bf16x8;
typedef __attribute__((ext_vector_type(4))) float f32x4;
typedef unsigned short ushort_t;

__device__ inline void bf16split(float v, ushort_t& h, ushort_t& l) {
    __hip_bfloat16 hb = __float2bfloat16(v);
    float hf = __bfloat162float(hb);
    __hip_bfloat16 lb = __float2bfloat16(v - hf);
    h = *reinterpret_cast<ushort_t*>(&hb);
    l = *reinterpret_cast<ushort_t*>(&lb);
}

// ---------------- Kernel A: cn = l2norm(codebook) + bf16 hi/lo split ----------------
__global__ void k_norm_cb(const float* __restrict__ cb, float* __restrict__ cn,
                          ushort_t* __restrict__ ch, ushort_t* __restrict__ cl) {
    int wv = threadIdx.x >> 6, lane = threadIdx.x & 63;
    int row = blockIdx.x * 4 + wv;
    float v = cb[(size_t)row * C_DIM + lane];
    float s = v * v;
    #pragma unroll
    for (int o = 32; o; o >>= 1) s += __shfl_xor(s, o, 64);
    float inv = 1.0f / fmaxf(sqrtf(s), EPSN);
    float nv = v * inv;
    size_t i = (size_t)row * C_DIM + lane;
    cn[i] = nv;
    ushort_t h, lo; bf16split(nv, h, lo);
    ch[i] = h; cl[i] = lo;
}

// ---------------- Kernel A2: w_outT[c][f] = w_out[f][c] ----------------
__global__ void k_transpose_wout(const float* __restrict__ w_out, float* __restrict__ wT) {
    int i = blockIdx.x * 256 + threadIdx.x;   // 49152 total
    int f = i >> 6, c = i & 63;
    wT[(size_t)c * F_DIM + f] = w_out[i];
}

// ---------------- Kernel B: zn = l2norm(z @ w_in^T) + bf16 hi/lo split ----------------
#define B_ROWS 32
#define B_KCH  128
__global__ void k_proj(const float* __restrict__ z, const float* __restrict__ w_in,
                       float* __restrict__ zn, ushort_t* __restrict__ zh,
                       ushort_t* __restrict__ zl) {
    __shared__ float lw[B_KCH][65];
    int wv = threadIdx.x >> 6, lane = threadIdx.x & 63;
    int m0 = blockIdx.x * B_ROWS + wv * 8;

    const float* zrow[8];
    #pragma unroll
    for (int r = 0; r < 8; ++r) {
        int mrow = __builtin_amdgcn_readfirstlane(m0 + r);
        zrow[r] = z + (size_t)mrow * F_DIM;
    }

    float acc[8];
    #pragma unroll
    for (int r = 0; r < 8; ++r) acc[r] = 0.0f;

    for (int k0 = 0; k0 < F_DIM; k0 += B_KCH) {
        int c  = threadIdx.x >> 2;
        int kp = (threadIdx.x & 3) * 32;
        const float4* src = (const float4*)(w_in + (size_t)c * F_DIM + k0 + kp);
        #pragma unroll
        for (int j = 0; j < 8; ++j) {
            float4 w4 = src[j];
            int k = kp + j * 4;
            lw[k + 0][c] = w4.x; lw[k + 1][c] = w4.y;
            lw[k + 2][c] = w4.z; lw[k + 3][c] = w4.w;
        }
        __syncthreads();
        for (int k = 0; k < B_KCH; k += 4) {
            float w0 = lw[k][lane], w1 = lw[k + 1][lane];
            float w2 = lw[k + 2][lane], w3 = lw[k + 3][lane];
            #pragma unroll
            for (int r = 0; r < 8; ++r) {
                float4 zv = *(const float4*)(zrow[r] + k0 + k);
                acc[r] = fmaf(zv.x, w0, acc[r]);
                acc[r] = fmaf(zv.y, w1, acc[r]);
                acc[r] = fmaf(zv.z, w2, acc[r]);
                acc[r] = fmaf(zv.w, w3, acc[r]);
            }
        }
        __syncthreads();
    }
    #pragma unroll
    for (int r = 0; r < 8; ++r) {
        float s = acc[r] * acc[r];
        #pragma unroll
        for (int o = 32; o; o >>= 1) s += __shfl_xor(s, o, 64);
        float inv = 1.0f / fmaxf(sqrtf(s), EPSN);
        float nv = acc[r] * inv;
        size_t i = (size_t)(m0 + r) * C_DIM + lane;
        zn[i] = nv;
        ushort_t h, lo; bf16split(nv, h, lo);
        zh[i] = h; zl[i] = lo;
    }
}

// ---------------- Kernel C: MFMA sim + argmax (best + second-best) ----------------
// block = 256 (4 waves); wave owns 64 m-rows (4 MFMA tiles), streams a 1024-p chunk.
// D[p][m] = cn[p]·zn[m] via bf16x3: ah*bh + al*bh + ah*bl. C/D: col=lane&15,
// row=(lane>>4)*4+reg  [guide §3, m89-verified]. A/B frag: 8 contiguous k per lane.
__global__ __launch_bounds__(256, 2)
void k_argmax_mfma(const ushort_t* __restrict__ zh, const ushort_t* __restrict__ zl,
                   const ushort_t* __restrict__ ch, const ushort_t* __restrict__ cl,
                   float* __restrict__ pb, float* __restrict__ pb2,
                   int* __restrict__ pbi) {
    int wv = threadIdx.x >> 6, l = threadIdx.x & 63;
    int m0 = (blockIdx.x * 4 + wv) * 64;
    int p0 = blockIdx.y * PCH;
    int col = l & 15, quad = l >> 4;
    int kb = quad * 8;

    // preload B fragments (zn hi/lo), 16 x 16B
    bf16x8 bh[4][2], bl[4][2];
    #pragma unroll
    for (int mt = 0; mt < 4; ++mt) {
        const ushort_t* zr  = zh + (size_t)(m0 + mt * 16 + col) * C_DIM + kb;
        const ushort_t* zr2 = zl + (size_t)(m0 + mt * 16 + col) * C_DIM + kb;
        #pragma unroll
        for (int ks = 0; ks < 2; ++ks) {
            bh[mt][ks] = *(const bf16x8*)(zr  + ks * 32);
            bl[mt][ks] = *(const bf16x8*)(zr2 + ks * 32);
        }
    }

    float best[4], best2[4]; int bi[4];
    #pragma unroll
    for (int mt = 0; mt < 4; ++mt) { best[mt] = NEG_BIG; best2[mt] = NEG_BIG; bi[mt] = 0; }

    for (int pt = 0; pt < PCH / 16; ++pt) {
        size_t prow = (size_t)(p0 + pt * 16 + col) * C_DIM + kb;
        bf16x8 ah0 = *(const bf16x8*)(ch + prow);
        bf16x8 ah1 = *(const bf16x8*)(ch + prow + 32);
        bf16x8 al0 = *(const bf16x8*)(cl + prow);
        bf16x8 al1 = *(const bf16x8*)(cl + prow + 32);
        #pragma unroll
        for (int mt = 0; mt < 4; ++mt) {
            f32x4 acc = {0.f, 0.f, 0.f, 0.f};
            acc = __builtin_amdgcn_mfma_f32_16x16x32_bf16(ah0, bh[mt][0], acc, 0, 0, 0);
            acc = __builtin_amdgcn_mfma_f32_16x16x32_bf16(al0, bh[mt][0], acc, 0, 0, 0);
            acc = __builtin_amdgcn_mfma_f32_16x16x32_bf16(ah0, bl[mt][0], acc, 0, 0, 0);
            acc = __builtin_amdgcn_mfma_f32_16x16x32_bf16(ah1, bh[mt][1], acc, 0, 0, 0);
            acc = __builtin_amdgcn_mfma_f32_16x16x32_bf16(al1, bh[mt][1], acc, 0, 0, 0);
            acc = __builtin_amdgcn_mfma_f32_16x16x32_bf16(ah1, bl[mt][1], acc, 0, 0, 0);
            #pragma unroll
            for (int r = 0; r < 4; ++r) {
                float s = acc[r];
                int p = pt * 16 + quad * 4 + r;     // ascending p per lane
                bool g = s > best[mt];              // strict >: lowest index wins
                best2[mt] = g ? best[mt] : fmaxf(best2[mt], s);
                best[mt]  = fmaxf(best[mt], s);
                bi[mt]    = g ? p : bi[mt];
            }
        }
    }

    // reduce across the 4 lanes (quads) sharing column m: lanes l^16, l^32
    #pragma unroll
    for (int mt = 0; mt < 4; ++mt) {
        float b = best[mt], b2 = best2[mt]; int i = bi[mt];
        #pragma unroll
        for (int off = 16; off <= 32; off <<= 1) {
            float ob  = __shfl_xor(b, off, 64);
            float ob2 = __shfl_xor(b2, off, 64);
            int   oi  = __shfl_xor(i, off, 64);
            if (ob > b)        { b2 = fmaxf(b, ob2); b = ob; i = oi; }
            else if (ob == b)  { b2 = b; i = min(i, oi); }
            else               { b2 = fmaxf(b2, ob); }
        }
        if (quad == 0) {
            int m = m0 + mt * 16 + col;
            pb [(size_t)m * NCH + blockIdx.y] = b;
            pb2[(size_t)m * NCH + blockIdx.y] = b2;
            pbi[(size_t)m * NCH + blockIdx.y] = p0 + i;
        }
    }
}

// ---------------- Kernel C2: merge chunks, flag near-ties for exact fallback ----------
__global__ void k_merge2(const float* __restrict__ pb, const float* __restrict__ pb2,
                         const int* __restrict__ pbi, int* __restrict__ idx_i,
                         float* __restrict__ idx_f, int* __restrict__ flist,
                         int* __restrict__ fcount) {
    int m = blockIdx.x * 256 + threadIdx.x;
    float b = NEG_BIG, b2 = NEG_BIG; int i = 0;
    #pragma unroll
    for (int c = 0; c < NCH; ++c) {   // ascending chunk: lowest index wins ties
        float ob  = pb [(size_t)m * NCH + c];
        float ob2 = pb2[(size_t)m * NCH + c];
        int   oi  = pbi[(size_t)m * NCH + c];
        if (ob > b)       { b2 = fmaxf(b, ob2); b = ob; i = oi; }
        else if (ob == b) { b2 = b; }
        else              { b2 = fmaxf(b2, ob); }
    }
    idx_i[m] = i;
    idx_f[m] = (float)i;
    if (b - b2 < TAU) {
        int s = atomicAdd(fcount, 1);
        flist[s] = m;
    }
}

// ---------------- Kernel C3: exact fp32 argmax for flagged rows ----------------
__global__ void k_fallback(const int* __restrict__ flist, const int* __restrict__ fcount,
                           const float* __restrict__ zn, const float* __restrict__ cn,
                           int* __restrict__ idx_i, float* __restrict__ idx_f) {
    int lane = threadIdx.x;
    int n = fcount[0];
    for (int t = blockIdx.x; t < n; t += 256) {
        int m = flist[t];
        float zr[64];
        #pragma unroll
        for (int j = 0; j < 16; ++j) {
            float4 v = *(const float4*)(zn + (size_t)m * C_DIM + j * 4);
            zr[4 * j] = v.x; zr[4 * j + 1] = v.y; zr[4 * j + 2] = v.z; zr[4 * j + 3] = v.w;
        }
        float best = NEG_BIG; int bi = 0;
        for (int p = lane; p < P_DIM; p += 64) {
            const float4* cp = (const float4*)(cn + (size_t)p * C_DIM);
            float a0 = 0.f, a1 = 0.f, a2 = 0.f, a3 = 0.f;
            #pragma unroll
            for (int j = 0; j < 16; ++j) {
                float4 w = cp[j];
                a0 = fmaf(w.x, zr[4 * j + 0], a0);
                a1 = fmaf(w.y, zr[4 * j + 1], a1);
                a2 = fmaf(w.z, zr[4 * j + 2], a2);
                a3 = fmaf(w.w, zr[4 * j + 3], a3);
            }
            float s = (a0 + a1) + (a2 + a3);
            if (s > best) { best = s; bi = p; }     // ascending p per lane
        }
        #pragma unroll
        for (int off = 32; off; off >>= 1) {
            float ob = __shfl_xor(best, off, 64);
            int   oi = __shfl_xor(bi, off, 64);
            if (ob > best || (ob == best && oi < bi)) { best = ob; bi = oi; }
        }
        if (lane == 0) { idx_i[m] = bi; idx_f[m] = (float)bi; }
    }
}

// ---------------- Kernel D: out = codes @ w_outT ----------------
#define D_ROWS 128
__global__ void k_out(const int* __restrict__ idx, const float* __restrict__ cn,
                      const float* __restrict__ wT, float* __restrict__ out) {
    int wv = threadIdx.x >> 6, lane = threadIdx.x & 63;
    int f  = blockIdx.y * 64 + lane;
    int m0 = blockIdx.x * D_ROWS + wv * 32;

    float wcol[64];
    #pragma unroll
    for (int c = 0; c < 64; ++c) wcol[c] = wT[(size_t)c * F_DIM + f];

    #pragma unroll 4
    for (int r = 0; r < 32; ++r) {
        int m = __builtin_amdgcn_readfirstlane(m0 + r);
        const float4* cp = (const float4*)(cn + (size_t)idx[m] * C_DIM);
        float acc = 0.f;
        #pragma unroll
        for (int j = 0; j < 16; ++j) {
            float4 cv = cp[j];
            acc = fmaf(cv.x, wcol[4 * j + 0], acc);
            acc = fmaf(cv.y, wcol[4 * j + 1], acc);
            acc = fmaf(cv.z, wcol[4 * j + 2], acc);
            acc = fmaf(cv.w, wcol[4 * j + 3], acc);
        }
        out[(size_t)m * F_DIM + f] = acc;
    }
}

// ---------------- Kernel E: per-block loss partials ----------------
__global__ void k_loss(const float* __restrict__ zn, const float* __restrict__ cn,
                       const int* __restrict__ idx, float* __restrict__ lossp) {
    __shared__ float wsum[4];
    int wv = threadIdx.x >> 6, lane = threadIdx.x & 63;
    int m = blockIdx.x * 4 + wv;
    int ci = idx[m];
    float zv = zn[(size_t)m * C_DIM + lane];
    float cv = cn[(size_t)ci * C_DIM + lane];
    float d = zv - cv;
    float s = d * d;
    #pragma unroll
    for (int o = 32; o; o >>= 1) s += __shfl_xor(s, o, 64);
    if (lane == 0) wsum[wv] = s;
    __syncthreads();
    if (threadIdx.x == 0) lossp[blockIdx.x] = (wsum[0] + wsum[1]) + (wsum[2] + wsum[3]);
}

__global__ void k_loss_final(const float* __restrict__ lossp, float* __restrict__ loss_out) {
    __shared__ float sh[256];
    float s = 0.f;
    for (int i = threadIdx.x; i < 4096; i += 256) s += lossp[i];
    sh[threadIdx.x] = s;
    __syncthreads();
    for (int o = 128; o; o >>= 1) {
        if (threadIdx.x < o) sh[threadIdx.x] += sh[threadIdx.x + o];
        __syncthreads();
    }
    if (threadIdx.x == 0)
        loss_out[0] = 1.25f * sh[0] / (float)(M_TOT * C_DIM);
}

extern "C" void kernel_launch(void* const* d_in, const int* in_sizes, int n_in,
                              void* d_out, int out_size, void* d_ws, size_t ws_size,
                              hipStream_t stream) {
    const float* z     = (const float*)d_in[0];
    const float* w_in  = (const float*)d_in[1];
    const float* w_out = (const float*)d_in[2];
    const float* cb    = (const float*)d_in[3];

    float* out    = (float*)d_out;
    float* lossO  = out + (size_t)M_TOT * F_DIM;
    float* idxO   = lossO + 1;

    float* ws    = (float*)d_ws;
    float* cn    = ws;                                    // 524288 f
    float* zn    = cn + (size_t)P_DIM * C_DIM;            // 1048576 f
    float* wT    = zn + (size_t)M_TOT * C_DIM;            // 49152 f
    float* lossp = wT + (size_t)C_DIM * F_DIM;            // 4096 f
    float* pb    = lossp + 4096;                          // 131072 f
    float* pb2   = pb + (size_t)M_TOT * NCH;              // 131072 f
    int*   pbi   = (int*)(pb2 + (size_t)M_TOT * NCH);     // 131072 i
    int*   idxi  = pbi + (size_t)M_TOT * NCH;             // 16384 i
    int*   flist = idxi + M_TOT;                          // 16384 i
    int*   fcount= flist + M_TOT;                         // 16 i (pad)
    ushort_t* zh = (ushort_t*)(fcount + 16);              // 1048576 us
    ushort_t* zl = zh + (size_t)M_TOT * C_DIM;            // 1048576 us
    ushort_t* ch = zl + (size_t)M_TOT * C_DIM;            // 524288 us
    ushort_t* cl = ch + (size_t)P_DIM * C_DIM;            // 524288 us

    hipMemsetAsync((void*)fcount, 0, 4, stream);

    k_norm_cb<<<P_DIM / 4, 256, 0, stream>>>(cb, cn, ch, cl);
    k_transpose_wout<<<(C_DIM * F_DIM) / 256, 256, 0, stream>>>(w_out, wT);
    k_proj<<<M_TOT / B_ROWS, 256, 0, stream>>>(z, w_in, zn, zh, zl);

    dim3 gC(M_TOT / 256, NCH);
    k_argmax_mfma<<<gC, 256, 0, stream>>>(zh, zl, ch, cl, pb, pb2, pbi);
    k_merge2<<<M_TOT / 256, 256, 0, stream>>>(pb, pb2, pbi, idxi, idxO, flist, fcount);
    k_fallback<<<256, 64, 0, stream>>>(flist, fcount, zn, cn, idxi, idxO);

    dim3 gD(M_TOT / D_ROWS, F_DIM / 64);
    k_out<<<gD, 256, 0, stream>>>(idxi, cn, wT, out);

    k_loss<<<M_TOT / 4, 256, 0, stream>>>(zn, cn, idxi, lossp);
    k_loss_final<<<1, 256, 0, stream>>>(lossp, lossO);
}

// Round 3
// 297.418 us; speedup vs baseline: 1.6642x; 1.6642x over previous
//
#include <hip/hip_runtime.h>
#include <hip/hip_bf16.h>
#include <math.h>

#define M_TOT   16384      // B*N = 4*4096
#define F_DIM   768
#define C_DIM   64
#define P_DIM   8192
#define EPSN    1e-12f
#define NEG_BIG (-3.402823466e38f)
#define NCH     8
#define PCH     (P_DIM / NCH)   // 1024
#define TAU     1e-4f          // bf16x3 per-sim error <= ~1e-5; 2 sims -> 2e-5; 5x margin

typedef __attribute__((ext_vector_type(8))) short bf16x8;
typedef __attribute__((ext_vector_type(4))) float f32x4;
typedef unsigned short ushort_t;

__device__ inline void bf16split(float v, ushort_t& h, ushort_t& l) {
    __hip_bfloat16 hb = __float2bfloat16(v);
    float hf = __bfloat162float(hb);
    __hip_bfloat16 lb = __float2bfloat16(v - hf);
    h = *reinterpret_cast<ushort_t*>(&hb);
    l = *reinterpret_cast<ushort_t*>(&lb);
}

// ---------------- Kernel A: cn = l2norm(codebook) + bf16 hi/lo split ----------------
__global__ void k_norm_cb(const float* __restrict__ cb, float* __restrict__ cn,
                          ushort_t* __restrict__ ch, ushort_t* __restrict__ cl) {
    int wv = threadIdx.x >> 6, lane = threadIdx.x & 63;
    int row = blockIdx.x * 4 + wv;
    float v = cb[(size_t)row * C_DIM + lane];
    float s = v * v;
    #pragma unroll
    for (int o = 32; o; o >>= 1) s += __shfl_xor(s, o, 64);
    float inv = 1.0f / fmaxf(sqrtf(s), EPSN);
    float nv = v * inv;
    size_t i = (size_t)row * C_DIM + lane;
    cn[i] = nv;
    ushort_t h, lo; bf16split(nv, h, lo);
    ch[i] = h; cl[i] = lo;
}

// ---------------- Kernel A2: w_outT[c][f] = w_out[f][c] ----------------
__global__ void k_transpose_wout(const float* __restrict__ w_out, float* __restrict__ wT) {
    int i = blockIdx.x * 256 + threadIdx.x;   // 49152 total
    int f = i >> 6, c = i & 63;
    wT[(size_t)c * F_DIM + f] = w_out[i];
}

// ---------------- Kernel B: zn = l2norm(z @ w_in^T) + bf16 hi/lo split ----------------
#define B_ROWS 32
#define B_KCH  128
__global__ void k_proj(const float* __restrict__ z, const float* __restrict__ w_in,
                       float* __restrict__ zn, ushort_t* __restrict__ zh,
                       ushort_t* __restrict__ zl) {
    __shared__ float lw[B_KCH][65];
    int wv = threadIdx.x >> 6, lane = threadIdx.x & 63;
    int m0 = blockIdx.x * B_ROWS + wv * 8;

    const float* zrow[8];
    #pragma unroll
    for (int r = 0; r < 8; ++r) {
        int mrow = __builtin_amdgcn_readfirstlane(m0 + r);
        zrow[r] = z + (size_t)mrow * F_DIM;
    }

    float acc[8];
    #pragma unroll
    for (int r = 0; r < 8; ++r) acc[r] = 0.0f;

    for (int k0 = 0; k0 < F_DIM; k0 += B_KCH) {
        int c  = threadIdx.x >> 2;
        int kp = (threadIdx.x & 3) * 32;
        const float4* src = (const float4*)(w_in + (size_t)c * F_DIM + k0 + kp);
        #pragma unroll
        for (int j = 0; j < 8; ++j) {
            float4 w4 = src[j];
            int k = kp + j * 4;
            lw[k + 0][c] = w4.x; lw[k + 1][c] = w4.y;
            lw[k + 2][c] = w4.z; lw[k + 3][c] = w4.w;
        }
        __syncthreads();
        for (int k = 0; k < B_KCH; k += 4) {
            float w0 = lw[k][lane], w1 = lw[k + 1][lane];
            float w2 = lw[k + 2][lane], w3 = lw[k + 3][lane];
            #pragma unroll
            for (int r = 0; r < 8; ++r) {
                float4 zv = *(const float4*)(zrow[r] + k0 + k);
                acc[r] = fmaf(zv.x, w0, acc[r]);
                acc[r] = fmaf(zv.y, w1, acc[r]);
                acc[r] = fmaf(zv.z, w2, acc[r]);
                acc[r] = fmaf(zv.w, w3, acc[r]);
            }
        }
        __syncthreads();
    }
    #pragma unroll
    for (int r = 0; r < 8; ++r) {
        float s = acc[r] * acc[r];
        #pragma unroll
        for (int o = 32; o; o >>= 1) s += __shfl_xor(s, o, 64);
        float inv = 1.0f / fmaxf(sqrtf(s), EPSN);
        float nv = acc[r] * inv;
        size_t i = (size_t)(m0 + r) * C_DIM + lane;
        zn[i] = nv;
        ushort_t h, lo; bf16split(nv, h, lo);
        zh[i] = h; zl[i] = lo;
    }
}

// ---------------- Kernel C: MFMA sim + argmax (best + second-best) ----------------
__global__ __launch_bounds__(256, 2)
void k_argmax_mfma(const ushort_t* __restrict__ zh, const ushort_t* __restrict__ zl,
                   const ushort_t* __restrict__ ch, const ushort_t* __restrict__ cl,
                   float* __restrict__ pb, float* __restrict__ pb2,
                   int* __restrict__ pbi) {
    int wv = threadIdx.x >> 6, l = threadIdx.x & 63;
    int m0 = (blockIdx.x * 4 + wv) * 64;
    int p0 = blockIdx.y * PCH;
    int col = l & 15, quad = l >> 4;
    int kb = quad * 8;

    bf16x8 bh[4][2], bl[4][2];
    #pragma unroll
    for (int mt = 0; mt < 4; ++mt) {
        const ushort_t* zr  = zh + (size_t)(m0 + mt * 16 + col) * C_DIM + kb;
        const ushort_t* zr2 = zl + (size_t)(m0 + mt * 16 + col) * C_DIM + kb;
        #pragma unroll
        for (int ks = 0; ks < 2; ++ks) {
            bh[mt][ks] = *(const bf16x8*)(zr  + ks * 32);
            bl[mt][ks] = *(const bf16x8*)(zr2 + ks * 32);
        }
    }

    float best[4], best2[4]; int bi[4];
    #pragma unroll
    for (int mt = 0; mt < 4; ++mt) { best[mt] = NEG_BIG; best2[mt] = NEG_BIG; bi[mt] = 0; }

    for (int pt = 0; pt < PCH / 16; ++pt) {
        size_t prow = (size_t)(p0 + pt * 16 + col) * C_DIM + kb;
        bf16x8 ah0 = *(const bf16x8*)(ch + prow);
        bf16x8 ah1 = *(const bf16x8*)(ch + prow + 32);
        bf16x8 al0 = *(const bf16x8*)(cl + prow);
        bf16x8 al1 = *(const bf16x8*)(cl + prow + 32);
        #pragma unroll
        for (int mt = 0; mt < 4; ++mt) {
            f32x4 acc = {0.f, 0.f, 0.f, 0.f};
            acc = __builtin_amdgcn_mfma_f32_16x16x32_bf16(ah0, bh[mt][0], acc, 0, 0, 0);
            acc = __builtin_amdgcn_mfma_f32_16x16x32_bf16(al0, bh[mt][0], acc, 0, 0, 0);
            acc = __builtin_amdgcn_mfma_f32_16x16x32_bf16(ah0, bl[mt][0], acc, 0, 0, 0);
            acc = __builtin_amdgcn_mfma_f32_16x16x32_bf16(ah1, bh[mt][1], acc, 0, 0, 0);
            acc = __builtin_amdgcn_mfma_f32_16x16x32_bf16(al1, bh[mt][1], acc, 0, 0, 0);
            acc = __builtin_amdgcn_mfma_f32_16x16x32_bf16(ah1, bl[mt][1], acc, 0, 0, 0);
            #pragma unroll
            for (int r = 0; r < 4; ++r) {
                float s = acc[r];
                int p = pt * 16 + quad * 4 + r;     // ascending p per lane
                bool g = s > best[mt];              // strict >: lowest index wins
                best2[mt] = g ? best[mt] : fmaxf(best2[mt], s);
                best[mt]  = fmaxf(best[mt], s);
                bi[mt]    = g ? p : bi[mt];
            }
        }
    }

    #pragma unroll
    for (int mt = 0; mt < 4; ++mt) {
        float b = best[mt], b2 = best2[mt]; int i = bi[mt];
        #pragma unroll
        for (int off = 16; off <= 32; off <<= 1) {
            float ob  = __shfl_xor(b, off, 64);
            float ob2 = __shfl_xor(b2, off, 64);
            int   oi  = __shfl_xor(i, off, 64);
            if (ob > b)        { b2 = fmaxf(b, ob2); b = ob; i = oi; }
            else if (ob == b)  { b2 = b; i = min(i, oi); }
            else               { b2 = fmaxf(b2, ob); }
        }
        if (quad == 0) {
            int m = m0 + mt * 16 + col;
            pb [(size_t)m * NCH + blockIdx.y] = b;
            pb2[(size_t)m * NCH + blockIdx.y] = b2;
            pbi[(size_t)m * NCH + blockIdx.y] = p0 + i;
        }
    }
}

// ---------------- Kernel C2: merge chunks, flag near-ties for exact fallback ----------
__global__ void k_merge2(const float* __restrict__ pb, const float* __restrict__ pb2,
                         const int* __restrict__ pbi, int* __restrict__ idx_i,
                         float* __restrict__ idx_f, int* __restrict__ flist,
                         int* __restrict__ fcount) {
    int m = blockIdx.x * 256 + threadIdx.x;
    float b = NEG_BIG, b2 = NEG_BIG; int i = 0;
    #pragma unroll
    for (int c = 0; c < NCH; ++c) {   // ascending chunk: lowest index wins ties
        float ob  = pb [(size_t)m * NCH + c];
        float ob2 = pb2[(size_t)m * NCH + c];
        int   oi  = pbi[(size_t)m * NCH + c];
        if (ob > b)       { b2 = fmaxf(b, ob2); b = ob; i = oi; }
        else if (ob == b) { b2 = b; }
        else              { b2 = fmaxf(b2, ob); }
    }
    idx_i[m] = i;
    idx_f[m] = (float)i;
    if (b - b2 < TAU) {
        int s = atomicAdd(fcount, 1);
        flist[s] = m;
    }
}

// ---------------- Kernel C3: exact fp32 argmax, one block per flagged row ----------
// 256 threads; thread t scans p = t, t+256, ... (32 codes, independent FMA chains).
__global__ void k_fallback(const int* __restrict__ flist, const int* __restrict__ fcount,
                           const float* __restrict__ zn, const float* __restrict__ cn,
                           int* __restrict__ idx_i, float* __restrict__ idx_f) {
    __shared__ float sv[4];
    __shared__ int   si[4];
    int tid = threadIdx.x, lane = tid & 63, wv = tid >> 6;
    int n = fcount[0];
    for (int t = blockIdx.x; t < n; t += gridDim.x) {
        int m = flist[t];
        float zr[64];
        #pragma unroll
        for (int j = 0; j < 16; ++j) {
            float4 v = *(const float4*)(zn + (size_t)m * C_DIM + j * 4);
            zr[4 * j] = v.x; zr[4 * j + 1] = v.y; zr[4 * j + 2] = v.z; zr[4 * j + 3] = v.w;
        }
        float best = NEG_BIG; int bi = P_DIM;
        for (int p = tid; p < P_DIM; p += 256) {     // ascending p per thread
            const float4* cp = (const float4*)(cn + (size_t)p * C_DIM);
            float a0 = 0.f, a1 = 0.f, a2 = 0.f, a3 = 0.f;
            #pragma unroll
            for (int j = 0; j < 16; ++j) {
                float4 w = cp[j];
                a0 = fmaf(w.x, zr[4 * j + 0], a0);
                a1 = fmaf(w.y, zr[4 * j + 1], a1);
                a2 = fmaf(w.z, zr[4 * j + 2], a2);
                a3 = fmaf(w.w, zr[4 * j + 3], a3);
            }
            float s = (a0 + a1) + (a2 + a3);
            if (s > best) { best = s; bi = p; }
        }
        #pragma unroll
        for (int off = 32; off; off >>= 1) {
            float ob = __shfl_xor(best, off, 64);
            int   oi = __shfl_xor(bi, off, 64);
            if (ob > best || (ob == best && oi < bi)) { best = ob; bi = oi; }
        }
        if (lane == 0) { sv[wv] = best; si[wv] = bi; }
        __syncthreads();
        if (tid == 0) {
            float b = sv[0]; int i = si[0];
            #pragma unroll
            for (int w = 1; w < 4; ++w)
                if (sv[w] > b || (sv[w] == b && si[w] < i)) { b = sv[w]; i = si[w]; }
            idx_i[m] = i; idx_f[m] = (float)i;
        }
        __syncthreads();
    }
}

// ---------------- Kernel D: out = codes @ w_outT ----------------
#define D_ROWS 128
__global__ void k_out(const int* __restrict__ idx, const float* __restrict__ cn,
                      const float* __restrict__ wT, float* __restrict__ out) {
    int wv = threadIdx.x >> 6, lane = threadIdx.x & 63;
    int f  = blockIdx.y * 64 + lane;
    int m0 = blockIdx.x * D_ROWS + wv * 32;

    float wcol[64];
    #pragma unroll
    for (int c = 0; c < 64; ++c) wcol[c] = wT[(size_t)c * F_DIM + f];

    #pragma unroll 4
    for (int r = 0; r < 32; ++r) {
        int m = __builtin_amdgcn_readfirstlane(m0 + r);
        const float4* cp = (const float4*)(cn + (size_t)idx[m] * C_DIM);
        float acc = 0.f;
        #pragma unroll
        for (int j = 0; j < 16; ++j) {
            float4 cv = cp[j];
            acc = fmaf(cv.x, wcol[4 * j + 0], acc);
            acc = fmaf(cv.y, wcol[4 * j + 1], acc);
            acc = fmaf(cv.z, wcol[4 * j + 2], acc);
            acc = fmaf(cv.w, wcol[4 * j + 3], acc);
        }
        out[(size_t)m * F_DIM + f] = acc;
    }
}

// ---------------- Kernel E: per-block loss partials ----------------
__global__ void k_loss(const float* __restrict__ zn, const float* __restrict__ cn,
                       const int* __restrict__ idx, float* __restrict__ lossp) {
    __shared__ float wsum[4];
    int wv = threadIdx.x >> 6, lane = threadIdx.x & 63;
    int m = blockIdx.x * 4 + wv;
    int ci = idx[m];
    float zv = zn[(size_t)m * C_DIM + lane];
    float cv = cn[(size_t)ci * C_DIM + lane];
    float d = zv - cv;
    float s = d * d;
    #pragma unroll
    for (int o = 32; o; o >>= 1) s += __shfl_xor(s, o, 64);
    if (lane == 0) wsum[wv] = s;
    __syncthreads();
    if (threadIdx.x == 0) lossp[blockIdx.x] = (wsum[0] + wsum[1]) + (wsum[2] + wsum[3]);
}

__global__ void k_loss_final(const float* __restrict__ lossp, float* __restrict__ loss_out) {
    __shared__ float sh[256];
    float s = 0.f;
    for (int i = threadIdx.x; i < 4096; i += 256) s += lossp[i];
    sh[threadIdx.x] = s;
    __syncthreads();
    for (int o = 128; o; o >>= 1) {
        if (threadIdx.x < o) sh[threadIdx.x] += sh[threadIdx.x + o];
        __syncthreads();
    }
    if (threadIdx.x == 0)
        loss_out[0] = 1.25f * sh[0] / (float)(M_TOT * C_DIM);
}

extern "C" void kernel_launch(void* const* d_in, const int* in_sizes, int n_in,
                              void* d_out, int out_size, void* d_ws, size_t ws_size,
                              hipStream_t stream) {
    const float* z     = (const float*)d_in[0];
    const float* w_in  = (const float*)d_in[1];
    const float* w_out = (const float*)d_in[2];
    const float* cb    = (const float*)d_in[3];

    float* out    = (float*)d_out;
    float* lossO  = out + (size_t)M_TOT * F_DIM;
    float* idxO   = lossO + 1;

    float* ws    = (float*)d_ws;
    float* cn    = ws;                                    // 524288 f
    float* zn    = cn + (size_t)P_DIM * C_DIM;            // 1048576 f
    float* wT    = zn + (size_t)M_TOT * C_DIM;            // 49152 f
    float* lossp = wT + (size_t)C_DIM * F_DIM;            // 4096 f
    float* pb    = lossp + 4096;                          // 131072 f
    float* pb2   = pb + (size_t)M_TOT * NCH;              // 131072 f
    int*   pbi   = (int*)(pb2 + (size_t)M_TOT * NCH);     // 131072 i
    int*   idxi  = pbi + (size_t)M_TOT * NCH;             // 16384 i
    int*   flist = idxi + M_TOT;                          // 16384 i
    int*   fcount= flist + M_TOT;                         // 16 i (pad)
    ushort_t* zh = (ushort_t*)(fcount + 16);              // 1048576 us
    ushort_t* zl = zh + (size_t)M_TOT * C_DIM;            // 1048576 us
    ushort_t* ch = zl + (size_t)M_TOT * C_DIM;            // 524288 us
    ushort_t* cl = ch + (size_t)P_DIM * C_DIM;            // 524288 us

    hipMemsetAsync((void*)fcount, 0, 4, stream);

    k_norm_cb<<<P_DIM / 4, 256, 0, stream>>>(cb, cn, ch, cl);
    k_transpose_wout<<<(C_DIM * F_DIM) / 256, 256, 0, stream>>>(w_out, wT);
    k_proj<<<M_TOT / B_ROWS, 256, 0, stream>>>(z, w_in, zn, zh, zl);

    dim3 gC(M_TOT / 256, NCH);
    k_argmax_mfma<<<gC, 256, 0, stream>>>(zh, zl, ch, cl, pb, pb2, pbi);
    k_merge2<<<M_TOT / 256, 256, 0, stream>>>(pb, pb2, pbi, idxi, idxO, flist, fcount);
    k_fallback<<<128, 256, 0, stream>>>(flist, fcount, zn, cn, idxi, idxO);

    dim3 gD(M_TOT / D_ROWS, F_DIM / 64);
    k_out<<<gD, 256, 0, stream>>>(idxi, cn, wT, out);

    k_loss<<<M_TOT / 4, 256, 0, stream>>>(zn, cn, idxi, lossp);
    k_loss_final<<<1, 256, 0, stream>>>(lossp, lossO);
}

// Round 4
// 248.910 us; speedup vs baseline: 1.9885x; 1.1949x over previous
//
#include <hip/hip_runtime.h>
#include <hip/hip_bf16.h>
#include <math.h>

#define M_TOT   16384      // B*N = 4*4096
#define F_DIM   768
#define C_DIM   64
#define P_DIM   8192
#define EPSN    1e-12f
#define NEG_BIG (-3.402823466e38f)
#define NCH     8
#define PCH     (P_DIM / NCH)   // 1024
#define TAU     1e-4f          // bf16x3 per-sim error <= ~1e-5; 2 sims -> 2e-5; 5x margin

typedef __attribute__((ext_vector_type(8))) short bf16x8;
typedef __attribute__((ext_vector_type(4))) float f32x4;
typedef unsigned short ushort_t;

__device__ inline void bf16split(float v, ushort_t& h, ushort_t& l) {
    __hip_bfloat16 hb = __float2bfloat16(v);
    float hf = __bfloat162float(hb);
    __hip_bfloat16 lb = __float2bfloat16(v - hf);
    h = *reinterpret_cast<ushort_t*>(&hb);
    l = *reinterpret_cast<ushort_t*>(&lb);
}

// ---------------- Kernel A: cn = l2norm(codebook) + bf16 hi/lo split ----------------
__global__ void k_norm_cb(const float* __restrict__ cb, float* __restrict__ cn,
                          ushort_t* __restrict__ ch, ushort_t* __restrict__ cl) {
    int wv = threadIdx.x >> 6, lane = threadIdx.x & 63;
    int row = blockIdx.x * 4 + wv;
    float v = cb[(size_t)row * C_DIM + lane];
    float s = v * v;
    #pragma unroll
    for (int o = 32; o; o >>= 1) s += __shfl_xor(s, o, 64);
    float inv = 1.0f / fmaxf(sqrtf(s), EPSN);
    float nv = v * inv;
    size_t i = (size_t)row * C_DIM + lane;
    cn[i] = nv;
    ushort_t h, lo; bf16split(nv, h, lo);
    ch[i] = h; cl[i] = lo;
}

// ---------------- Kernel A2: w_outT[c][f] = w_out[f][c] ----------------
__global__ void k_transpose_wout(const float* __restrict__ w_out, float* __restrict__ wT) {
    int i = blockIdx.x * 256 + threadIdx.x;   // 49152 total
    int f = i >> 6, c = i & 63;
    wT[(size_t)c * F_DIM + f] = w_out[i];
}

// ---------------- Kernel B: zn = l2norm(z @ w_in^T), tiled LDS fp32 GEMM ----------
// tile 32(m) x 64(c), 128 threads, thread = 4x4 register block, KC=128.
// LDS layout: 16B-unit XOR swizzle (k4 ^ ((row>>2)&7)) -> staging writes and
// compute reads are all <=2-way (free). z staged coalesced float4.
#define PBM 32
#define PKC 128
__global__ __launch_bounds__(128)
void k_proj(const float* __restrict__ z, const float* __restrict__ w_in,
            float* __restrict__ zn, ushort_t* __restrict__ zh,
            ushort_t* __restrict__ zl) {
    __shared__ float lz[PBM * PKC];     // 16 KB, [row][swz(k4)*4]
    __shared__ float lw[C_DIM * PKC];   // 32 KB, [c][swz(k4)*4]

    const int t  = threadIdx.x;
    const int m0 = blockIdx.x * PBM;
    const int r0 = (t >> 4) * 4;        // rows r0..r0+3   (t>>4 in 0..7)
    const int c0 = (t & 15) * 4;        // cols c0..c0+3

    float acc[4][4];
    #pragma unroll
    for (int i = 0; i < 4; ++i)
        #pragma unroll
        for (int j = 0; j < 4; ++j) acc[i][j] = 0.0f;

    const int zswz = (t >> 4) & 7;      // ((r0+ri)>>2)&7, same for ri=0..3
    const int wswz = t & 7;             // ((c0+cj)>>2)&7, same for cj=0..3

    for (int k0 = 0; k0 < F_DIM; k0 += PKC) {
        // ---- stage z tile: 32 rows x 128 k = 1024 float4, 8 per thread ----
        #pragma unroll
        for (int i = 0; i < 8; ++i) {
            int f4  = i * 128 + t;
            int row = f4 >> 5, k4 = f4 & 31;
            float4 v = *(const float4*)(z + (size_t)(m0 + row) * F_DIM + k0 + k4 * 4);
            *(float4*)(lz + row * PKC + ((k4 ^ ((row >> 2) & 7)) * 4)) = v;
        }
        // ---- stage w tile: 64 c x 128 k = 2048 float4, 16 per thread ----
        #pragma unroll
        for (int i = 0; i < 16; ++i) {
            int f4 = i * 128 + t;
            int c  = f4 >> 5, k4 = f4 & 31;
            float4 v = *(const float4*)(w_in + (size_t)c * F_DIM + k0 + k4 * 4);
            *(float4*)(lw + c * PKC + ((k4 ^ ((c >> 2) & 7)) * 4)) = v;
        }
        __syncthreads();

        #pragma unroll 4
        for (int kq = 0; kq < 32; ++kq) {
            float4 zf[4], wf[4];
            int zo = (kq ^ zswz) * 4;
            int wo = (kq ^ wswz) * 4;
            #pragma unroll
            for (int ri = 0; ri < 4; ++ri)
                zf[ri] = *(const float4*)(lz + (r0 + ri) * PKC + zo);
            #pragma unroll
            for (int cj = 0; cj < 4; ++cj)
                wf[cj] = *(const float4*)(lw + (c0 + cj) * PKC + wo);
            #pragma unroll
            for (int ri = 0; ri < 4; ++ri)
                #pragma unroll
                for (int cj = 0; cj < 4; ++cj) {
                    acc[ri][cj] = fmaf(zf[ri].x, wf[cj].x, acc[ri][cj]);
                    acc[ri][cj] = fmaf(zf[ri].y, wf[cj].y, acc[ri][cj]);
                    acc[ri][cj] = fmaf(zf[ri].z, wf[cj].z, acc[ri][cj]);
                    acc[ri][cj] = fmaf(zf[ri].w, wf[cj].w, acc[ri][cj]);
                }
        }
        __syncthreads();
    }

    // ---- epilogue: row-norm (16-lane group holds one row's 64 c) ----
    #pragma unroll
    for (int ri = 0; ri < 4; ++ri) {
        float s = acc[ri][0] * acc[ri][0] + acc[ri][1] * acc[ri][1]
                + acc[ri][2] * acc[ri][2] + acc[ri][3] * acc[ri][3];
        #pragma unroll
        for (int o = 1; o < 16; o <<= 1) s += __shfl_xor(s, o, 64);
        float inv = 1.0f / fmaxf(sqrtf(s), EPSN);
        float4 v;
        v.x = acc[ri][0] * inv; v.y = acc[ri][1] * inv;
        v.z = acc[ri][2] * inv; v.w = acc[ri][3] * inv;
        size_t base = (size_t)(m0 + r0 + ri) * C_DIM + c0;
        *(float4*)(zn + base) = v;
        ushort_t h0, l0, h1, l1, h2, l2, h3, l3;
        bf16split(v.x, h0, l0); bf16split(v.y, h1, l1);
        bf16split(v.z, h2, l2); bf16split(v.w, h3, l3);
        ushort4 hv = {h0, h1, h2, h3}, lv = {l0, l1, l2, l3};
        *(ushort4*)(zh + base) = hv;
        *(ushort4*)(zl + base) = lv;
    }
}

// ---------------- Kernel C: MFMA sim + argmax (best + second-best) ----------------
__global__ __launch_bounds__(256, 2)
void k_argmax_mfma(const ushort_t* __restrict__ zh, const ushort_t* __restrict__ zl,
                   const ushort_t* __restrict__ ch, const ushort_t* __restrict__ cl,
                   float* __restrict__ pb, float* __restrict__ pb2,
                   int* __restrict__ pbi) {
    int wv = threadIdx.x >> 6, l = threadIdx.x & 63;
    int m0 = (blockIdx.x * 4 + wv) * 64;
    int p0 = blockIdx.y * PCH;
    int col = l & 15, quad = l >> 4;
    int kb = quad * 8;

    bf16x8 bh[4][2], bl[4][2];
    #pragma unroll
    for (int mt = 0; mt < 4; ++mt) {
        const ushort_t* zr  = zh + (size_t)(m0 + mt * 16 + col) * C_DIM + kb;
        const ushort_t* zr2 = zl + (size_t)(m0 + mt * 16 + col) * C_DIM + kb;
        #pragma unroll
        for (int ks = 0; ks < 2; ++ks) {
            bh[mt][ks] = *(const bf16x8*)(zr  + ks * 32);
            bl[mt][ks] = *(const bf16x8*)(zr2 + ks * 32);
        }
    }

    float best[4], best2[4]; int bi[4];
    #pragma unroll
    for (int mt = 0; mt < 4; ++mt) { best[mt] = NEG_BIG; best2[mt] = NEG_BIG; bi[mt] = 0; }

    for (int pt = 0; pt < PCH / 16; ++pt) {
        size_t prow = (size_t)(p0 + pt * 16 + col) * C_DIM + kb;
        bf16x8 ah0 = *(const bf16x8*)(ch + prow);
        bf16x8 ah1 = *(const bf16x8*)(ch + prow + 32);
        bf16x8 al0 = *(const bf16x8*)(cl + prow);
        bf16x8 al1 = *(const bf16x8*)(cl + prow + 32);
        #pragma unroll
        for (int mt = 0; mt < 4; ++mt) {
            f32x4 acc = {0.f, 0.f, 0.f, 0.f};
            acc = __builtin_amdgcn_mfma_f32_16x16x32_bf16(ah0, bh[mt][0], acc, 0, 0, 0);
            acc = __builtin_amdgcn_mfma_f32_16x16x32_bf16(al0, bh[mt][0], acc, 0, 0, 0);
            acc = __builtin_amdgcn_mfma_f32_16x16x32_bf16(ah0, bl[mt][0], acc, 0, 0, 0);
            acc = __builtin_amdgcn_mfma_f32_16x16x32_bf16(ah1, bh[mt][1], acc, 0, 0, 0);
            acc = __builtin_amdgcn_mfma_f32_16x16x32_bf16(al1, bh[mt][1], acc, 0, 0, 0);
            acc = __builtin_amdgcn_mfma_f32_16x16x32_bf16(ah1, bl[mt][1], acc, 0, 0, 0);
            #pragma unroll
            for (int r = 0; r < 4; ++r) {
                float s = acc[r];
                int p = pt * 16 + quad * 4 + r;     // ascending p per lane
                bool g = s > best[mt];              // strict >: lowest index wins
                best2[mt] = g ? best[mt] : fmaxf(best2[mt], s);
                best[mt]  = fmaxf(best[mt], s);
                bi[mt]    = g ? p : bi[mt];
            }
        }
    }

    #pragma unroll
    for (int mt = 0; mt < 4; ++mt) {
        float b = best[mt], b2 = best2[mt]; int i = bi[mt];
        #pragma unroll
        for (int off = 16; off <= 32; off <<= 1) {
            float ob  = __shfl_xor(b, off, 64);
            float ob2 = __shfl_xor(b2, off, 64);
            int   oi  = __shfl_xor(i, off, 64);
            if (ob > b)        { b2 = fmaxf(b, ob2); b = ob; i = oi; }
            else if (ob == b)  { b2 = b; i = min(i, oi); }
            else               { b2 = fmaxf(b2, ob); }
        }
        if (quad == 0) {
            int m = m0 + mt * 16 + col;
            pb [(size_t)m * NCH + blockIdx.y] = b;
            pb2[(size_t)m * NCH + blockIdx.y] = b2;
            pbi[(size_t)m * NCH + blockIdx.y] = p0 + i;
        }
    }
}

// ---------------- Kernel C2: merge chunks, flag near-ties for exact fallback ----------
__global__ void k_merge2(const float* __restrict__ pb, const float* __restrict__ pb2,
                         const int* __restrict__ pbi, int* __restrict__ idx_i,
                         float* __restrict__ idx_f, int* __restrict__ flist,
                         int* __restrict__ fcount) {
    int m = blockIdx.x * 256 + threadIdx.x;
    float b = NEG_BIG, b2 = NEG_BIG; int i = 0;
    #pragma unroll
    for (int c = 0; c < NCH; ++c) {   // ascending chunk: lowest index wins ties
        float ob  = pb [(size_t)m * NCH + c];
        float ob2 = pb2[(size_t)m * NCH + c];
        int   oi  = pbi[(size_t)m * NCH + c];
        if (ob > b)       { b2 = fmaxf(b, ob2); b = ob; i = oi; }
        else if (ob == b) { b2 = b; }
        else              { b2 = fmaxf(b2, ob); }
    }
    idx_i[m] = i;
    idx_f[m] = (float)i;
    if (b - b2 < TAU) {
        int s = atomicAdd(fcount, 1);
        flist[s] = m;
    }
}

// ---------------- Kernel C3: exact fp32 argmax, one block per flagged row ----------
__global__ void k_fallback(const int* __restrict__ flist, const int* __restrict__ fcount,
                           const float* __restrict__ zn, const float* __restrict__ cn,
                           int* __restrict__ idx_i, float* __restrict__ idx_f) {
    __shared__ float sv[4];
    __shared__ int   si[4];
    int tid = threadIdx.x, lane = tid & 63, wv = tid >> 6;
    int n = fcount[0];
    for (int t = blockIdx.x; t < n; t += gridDim.x) {
        int m = flist[t];
        float zr[64];
        #pragma unroll
        for (int j = 0; j < 16; ++j) {
            float4 v = *(const float4*)(zn + (size_t)m * C_DIM + j * 4);
            zr[4 * j] = v.x; zr[4 * j + 1] = v.y; zr[4 * j + 2] = v.z; zr[4 * j + 3] = v.w;
        }
        float best = NEG_BIG; int bi = P_DIM;
        for (int p = tid; p < P_DIM; p += 256) {     // ascending p per thread
            const float4* cp = (const float4*)(cn + (size_t)p * C_DIM);
            float a0 = 0.f, a1 = 0.f, a2 = 0.f, a3 = 0.f;
            #pragma unroll
            for (int j = 0; j < 16; ++j) {
                float4 w = cp[j];
                a0 = fmaf(w.x, zr[4 * j + 0], a0);
                a1 = fmaf(w.y, zr[4 * j + 1], a1);
                a2 = fmaf(w.z, zr[4 * j + 2], a2);
                a3 = fmaf(w.w, zr[4 * j + 3], a3);
            }
            float s = (a0 + a1) + (a2 + a3);
            if (s > best) { best = s; bi = p; }
        }
        #pragma unroll
        for (int off = 32; off; off >>= 1) {
            float ob = __shfl_xor(best, off, 64);
            int   oi = __shfl_xor(bi, off, 64);
            if (ob > best || (ob == best && oi < bi)) { best = ob; bi = oi; }
        }
        if (lane == 0) { sv[wv] = best; si[wv] = bi; }
        __syncthreads();
        if (tid == 0) {
            float b = sv[0]; int i = si[0];
            #pragma unroll
            for (int w = 1; w < 4; ++w)
                if (sv[w] > b || (sv[w] == b && si[w] < i)) { b = sv[w]; i = si[w]; }
            idx_i[m] = i; idx_f[m] = (float)i;
        }
        __syncthreads();
    }
}

// ---------------- Kernel D: out = codes @ w_outT ----------------
#define D_ROWS 128
__global__ void k_out(const int* __restrict__ idx, const float* __restrict__ cn,
                      const float* __restrict__ wT, float* __restrict__ out) {
    int wv = threadIdx.x >> 6, lane = threadIdx.x & 63;
    int f  = blockIdx.y * 64 + lane;
    int m0 = blockIdx.x * D_ROWS + wv * 32;

    float wcol[64];
    #pragma unroll
    for (int c = 0; c < 64; ++c) wcol[c] = wT[(size_t)c * F_DIM + f];

    #pragma unroll 4
    for (int r = 0; r < 32; ++r) {
        int m = __builtin_amdgcn_readfirstlane(m0 + r);
        const float4* cp = (const float4*)(cn + (size_t)idx[m] * C_DIM);
        float acc = 0.f;
        #pragma unroll
        for (int j = 0; j < 16; ++j) {
            float4 cv = cp[j];
            acc = fmaf(cv.x, wcol[4 * j + 0], acc);
            acc = fmaf(cv.y, wcol[4 * j + 1], acc);
            acc = fmaf(cv.z, wcol[4 * j + 2], acc);
            acc = fmaf(cv.w, wcol[4 * j + 3], acc);
        }
        out[(size_t)m * F_DIM + f] = acc;
    }
}

// ---------------- Kernel E: per-block loss partials ----------------
__global__ void k_loss(const float* __restrict__ zn, const float* __restrict__ cn,
                       const int* __restrict__ idx, float* __restrict__ lossp) {
    __shared__ float wsum[4];
    int wv = threadIdx.x >> 6, lane = threadIdx.x & 63;
    int m = blockIdx.x * 4 + wv;
    int ci = idx[m];
    float zv = zn[(size_t)m * C_DIM + lane];
    float cv = cn[(size_t)ci * C_DIM + lane];
    float d = zv - cv;
    float s = d * d;
    #pragma unroll
    for (int o = 32; o; o >>= 1) s += __shfl_xor(s, o, 64);
    if (lane == 0) wsum[wv] = s;
    __syncthreads();
    if (threadIdx.x == 0) lossp[blockIdx.x] = (wsum[0] + wsum[1]) + (wsum[2] + wsum[3]);
}

__global__ void k_loss_final(const float* __restrict__ lossp, float* __restrict__ loss_out) {
    __shared__ float sh[256];
    float s = 0.f;
    for (int i = threadIdx.x; i < 4096; i += 256) s += lossp[i];
    sh[threadIdx.x] = s;
    __syncthreads();
    for (int o = 128; o; o >>= 1) {
        if (threadIdx.x < o) sh[threadIdx.x] += sh[threadIdx.x + o];
        __syncthreads();
    }
    if (threadIdx.x == 0)
        loss_out[0] = 1.25f * sh[0] / (float)(M_TOT * C_DIM);
}

extern "C" void kernel_launch(void* const* d_in, const int* in_sizes, int n_in,
                              void* d_out, int out_size, void* d_ws, size_t ws_size,
                              hipStream_t stream) {
    const float* z     = (const float*)d_in[0];
    const float* w_in  = (const float*)d_in[1];
    const float* w_out = (const float*)d_in[2];
    const float* cb    = (const float*)d_in[3];

    float* out    = (float*)d_out;
    float* lossO  = out + (size_t)M_TOT * F_DIM;
    float* idxO   = lossO + 1;

    float* ws    = (float*)d_ws;
    float* cn    = ws;                                    // 524288 f
    float* zn    = cn + (size_t)P_DIM * C_DIM;            // 1048576 f
    float* wT    = zn + (size_t)M_TOT * C_DIM;            // 49152 f
    float* lossp = wT + (size_t)C_DIM * F_DIM;            // 4096 f
    float* pb    = lossp + 4096;                          // 131072 f
    float* pb2   = pb + (size_t)M_TOT * NCH;              // 131072 f
    int*   pbi   = (int*)(pb2 + (size_t)M_TOT * NCH);     // 131072 i
    int*   idxi  = pbi + (size_t)M_TOT * NCH;             // 16384 i
    int*   flist = idxi + M_TOT;                          // 16384 i
    int*   fcount= flist + M_TOT;                         // 16 i (pad)
    ushort_t* zh = (ushort_t*)(fcount + 16);              // 1048576 us
    ushort_t* zl = zh + (size_t)M_TOT * C_DIM;            // 1048576 us
    ushort_t* ch = zl + (size_t)M_TOT * C_DIM;            // 524288 us
    ushort_t* cl = ch + (size_t)P_DIM * C_DIM;            // 524288 us

    hipMemsetAsync((void*)fcount, 0, 4, stream);

    k_norm_cb<<<P_DIM / 4, 256, 0, stream>>>(cb, cn, ch, cl);
    k_transpose_wout<<<(C_DIM * F_DIM) / 256, 256, 0, stream>>>(w_out, wT);
    k_proj<<<M_TOT / PBM, 128, 0, stream>>>(z, w_in, zn, zh, zl);

    dim3 gC(M_TOT / 256, NCH);
    k_argmax_mfma<<<gC, 256, 0, stream>>>(zh, zl, ch, cl, pb, pb2, pbi);
    k_merge2<<<M_TOT / 256, 256, 0, stream>>>(pb, pb2, pbi, idxi, idxO, flist, fcount);
    k_fallback<<<128, 256, 0, stream>>>(flist, fcount, zn, cn, idxi, idxO);

    dim3 gD(M_TOT / D_ROWS, F_DIM / 64);
    k_out<<<gD, 256, 0, stream>>>(idxi, cn, wT, out);

    k_loss<<<M_TOT / 4, 256, 0, stream>>>(zn, cn, idxi, lossp);
    k_loss_final<<<1, 256, 0, stream>>>(lossp, lossO);
}